// Round 11
// baseline (319.935 us; speedup 1.0000x reference)
//
#include <hip/hip_runtime.h>
#include <hip/hip_bf16.h>

#define DD 128
#define TILE_BYTES 32768
#define WS_R_OFF   196608            // 6 tiles * 32768
#define WS_GB_OFF  199168            // + 640*4 (R')

typedef __attribute__((ext_vector_type(8))) short bf16x8;
typedef __attribute__((ext_vector_type(4))) float f32x4;

__device__ inline unsigned short f2bf(float f) {
  unsigned u = __float_as_uint(f);
  return (unsigned short)((u + 0x7fffu + ((u >> 16) & 1u)) >> 16);   // RNE
}
__device__ inline float bf2f_lo(unsigned v) { return __uint_as_float(v << 16); }
__device__ inline float bf2f_hi(unsigned v) { return __uint_as_float(v & 0xffff0000u); }

// async global->LDS, 16B per lane; LDS dest is wave-uniform base + lane*16
__device__ inline void async16(void* ldsp, const void* gp) {
  __builtin_amdgcn_global_load_lds(
      (const __attribute__((address_space(1))) void*)gp,
      (__attribute__((address_space(3))) void*)ldsp, 16, 0, 0);
}

// fill a 32 KB LDS slot from a pre-swizzled global image (256 threads)
__device__ inline void fill_w(char* slot, const char* src, int tid) {
  int w = tid >> 6, lane = tid & 63;
  #pragma unroll
  for (int i = 0; i < 8; ++i) {
    int ofs = ((i << 2) + w) << 10;            // 1 KB per wave-chunk
    async16(slot + ofs, src + ofs + lane * 16);
  }
}

// same, with 512 threads (8 waves x 4 sweeps x 1 KB)
__device__ inline void fill512(char* slot, const char* src, int tid) {
  int w = tid >> 6, lane = tid & 63;
  #pragma unroll
  for (int i = 0; i < 4; ++i) {
    int ofs = ((i << 3) + w) << 10;
    async16(slot + ofs, src + ofs + lane * 16);
  }
}

// read a 16x32 bf16 MFMA fragment from a swizzled [rows][128] bf16 tile (LDS)
__device__ inline bf16x8 ldfrag(const char* buf, int rowbase, int kk, int lane) {
  int row = rowbase + (lane & 15);
  int off = (row << 8) + (kk << 6) + (lane & 48);
  off ^= (row & 7) << 4;
  return *(const bf16x8*)(buf + off);
}

// same addressing, global pre-swizzled tile image (L2-hot)
__device__ inline bf16x8 ldfragG(const char* gbuf, int rowbase, int kk, int lane) {
  int row = rowbase + (lane & 15);
  int off = (row << 8) + (kk << 6) + (lane & 48);
  off ^= (row & 7) << 4;
  return *(const bf16x8*)(gbuf + off);
}

// build a fragment directly from a global fp32 row (8 floats -> bf16x8)
__device__ inline bf16x8 ldAg(const float* rp, int kk, int lane) {
  const float4* p = (const float4*)(rp + (kk << 5) + ((lane >> 4) << 3));
  float4 f0 = p[0], f1 = p[1];
  bf16x8 r;
  r[0] = (short)f2bf(f0.x); r[1] = (short)f2bf(f0.y);
  r[2] = (short)f2bf(f0.z); r[3] = (short)f2bf(f0.w);
  r[4] = (short)f2bf(f1.x); r[5] = (short)f2bf(f1.y);
  r[6] = (short)f2bf(f1.z); r[7] = (short)f2bf(f1.w);
  return r;
}

__device__ inline uint2 pack4(float v0, float v1, float v2, float v3) {
  return make_uint2((unsigned)f2bf(v0) | ((unsigned)f2bf(v1) << 16),
                    (unsigned)f2bf(v2) | ((unsigned)f2bf(v3) << 16));
}

#define MFMA(a, b, c) __builtin_amdgcn_mfma_f32_16x16x32_bf16((a), (b), (c), 0, 0, 0)

// ---------------- pre-kernel 1: weight tiles (bf16, [n][k], pre-swizzled) + R' ----------------
__global__ __launch_bounds__(256) void prep_weights(
    const float* __restrict__ W1, const float* __restrict__ W2,
    const float* __restrict__ a1W, const float* __restrict__ a2W,
    const float* __restrict__ geW,
    const float* __restrict__ r2e, const float* __restrict__ b1,
    unsigned short* __restrict__ wsw, float* __restrict__ Rp) {
  int gid = blockIdx.x * 256 + threadIdx.x;
  if (gid < 12288) {
    int tile = gid >> 11, idx = gid & 2047;
    int row = idx >> 4, slot = idx & 15;
    int slot2 = slot ^ (row & 7);              // inverse swizzle on source
    const float* W; int kb;
    switch (tile) {
      case 0:  W = W1;  kb = 0;   break;       // W1[:128]
      case 1:  W = W2;  kb = 0;   break;
      case 2:  W = a1W; kb = 0;   break;       // a1W[:128]
      case 3:  W = a2W; kb = 0;   break;
      case 4:  W = geW; kb = 0;   break;
      default: W = a1W; kb = 128; break;       // a1W[128:]
    }
    unsigned pk[4];
    #pragma unroll
    for (int p = 0; p < 4; ++p) {
      unsigned short lo = f2bf(W[(size_t)(kb + slot2 * 8 + 2 * p) * DD + row]);
      unsigned short hi = f2bf(W[(size_t)(kb + slot2 * 8 + 2 * p + 1) * DD + row]);
      pk[p] = (unsigned)lo | ((unsigned)hi << 16);
    }
    *(uint4*)(wsw + (size_t)tile * 16384 + (size_t)idx * 8) =
        make_uint4(pk[0], pk[1], pk[2], pk[3]);
  } else {
    // R'[5][128] = r2e @ W1[128:] + b1   (fp32 exact)
    int t = gid - 12288;
    for (int idx = t; idx < 640; idx += 256) {
      int r = idx >> 7, d = idx & 127;
      float s = b1[d];
      for (int k = 0; k < 128; ++k)
        s = fmaf(r2e[r * DD + k], W1[(size_t)(DD + k) * DD + d], s);
      Rp[idx] = s;
    }
  }
}

// ---------------- pre-kernel 2: gb[b][d] = a1b + relu(mean@geW+geb)@a1W[D:] ----------------
__global__ __launch_bounds__(256, 2) void prep_gb(
    const int* __restrict__ nodes, const float* __restrict__ u2e,
    const float* __restrict__ geb, const float* __restrict__ a1b,
    const char* __restrict__ tiles, float* __restrict__ gbv) {
  __shared__ char mean_s[4096];    // [16][128] bf16 swizzled
  __shared__ char g_s[4096];
  __shared__ char wslot[32768];
  __shared__ int nodes_s[128];
  int tid = threadIdx.x, w = tid >> 6, lane = tid & 63;
  int b0 = blockIdx.x * 16;
  if (tid < 128) nodes_s[tid] = nodes[b0 * 8 + tid];
  fill_w(wslot, tiles + 4 * TILE_BYTES, tid);      // geW
  __syncthreads();
  for (int idx = tid; idx < 2048; idx += 256) {
    int row = idx >> 7, d = idx & 127;
    float m = 0.f;
    #pragma unroll
    for (int j = 0; j < 8; ++j)
      m += u2e[(size_t)nodes_s[row * 8 + j] * DD + d];
    m *= 0.125f;
    int off = ((row << 8) + (d << 1)) ^ ((row & 7) << 4);
    *(unsigned short*)(mean_s + off) = f2bf(m);
  }
  __syncthreads();
  int cb = lane & 15, rb = (lane >> 4) << 2;
  f32x4 acc[2] = {(f32x4)(0.f), (f32x4)(0.f)};
  #pragma unroll
  for (int kk = 0; kk < 4; ++kk) {
    bf16x8 a = ldfrag(mean_s, 0, kk, lane);
    #pragma unroll
    for (int nf = 0; nf < 2; ++nf) {
      bf16x8 b = ldfrag(wslot, w * 32 + nf * 16, kk, lane);
      acc[nf] = MFMA(a, b, acc[nf]);
    }
  }
  __syncthreads();
  fill_w(wslot, tiles + 5 * TILE_BYTES, tid);      // a1W[128:]
  #pragma unroll
  for (int nf = 0; nf < 2; ++nf) {
    int col = w * 32 + nf * 16 + cb;
    float gb2 = geb[col];
    #pragma unroll
    for (int j = 0; j < 4; ++j) {
      int row = rb + j;
      float v = fmaxf(acc[nf][j] + gb2, 0.f);
      int off = ((row << 8) + (col << 1)) ^ ((row & 7) << 4);
      *(unsigned short*)(g_s + off) = f2bf(v);
    }
  }
  __syncthreads();
  acc[0] = (f32x4)(0.f); acc[1] = (f32x4)(0.f);
  #pragma unroll
  for (int kk = 0; kk < 4; ++kk) {
    bf16x8 a = ldfrag(g_s, 0, kk, lane);
    #pragma unroll
    for (int nf = 0; nf < 2; ++nf) {
      bf16x8 b = ldfrag(wslot, w * 32 + nf * 16, kk, lane);
      acc[nf] = MFMA(a, b, acc[nf]);
    }
  }
  #pragma unroll
  for (int nf = 0; nf < 2; ++nf) {
    int col = w * 32 + nf * 16 + cb;
    float bb = a1b[col];
    #pragma unroll
    for (int j = 0; j < 4; ++j)
      gbv[(size_t)(b0 + rb + j) * DD + col] = acc[nf][j] + bb;
  }
}

// ---------------- main: wave-private chain, 128f x 32l per wave, 2 barriers/iter ----------------
__global__ __launch_bounds__(512, 1) void main_kernel(
    const int* __restrict__ hu, const int* __restrict__ hr,
    const int* __restrict__ hlen,
    const float* __restrict__ v2e,
    const float* __restrict__ b2, const float* __restrict__ a2b,
    const float* __restrict__ a3W, const float* __restrict__ a3b,
    const char* __restrict__ tiles, const float* __restrict__ Rp,
    const float* __restrict__ gbv, float* __restrict__ out) {
  __shared__ char smem[137216];
  char*  W2s   = smem;                    // 32 KB resident (G2 A)
  char*  A1s   = smem + 32768;            // 32 KB resident (G3 A)
  char*  Xall  = smem + 65536;            // 8 waves x 8 KB private slices
  float* lpart = (float*)(smem + 131072); // [4 rows][64]
  float* red   = (float*)(smem + 132096); // [4 rows][2 wl][128]

  const int tid = threadIdx.x, lane = tid & 63;
  const int wv = tid >> 6;               // 0..7
  const int ri = wv >> 1;                // row-in-iteration 0..3
  const int wl = wv & 1;                 // l-half of the row
  const int cb = lane & 15, g = lane >> 4;
  char* X = Xall + wv * 8192;            // wave-private [32 ll][256B], swizzled
  const char* W1g = tiles;               // global pre-swizzled W1 image (G1 A)
  const char* A2g = tiles + 3 * TILE_BYTES;  // global a2W image (G4 A)
  const float a3bv = a3b[0];

  fill512(W2s, tiles + TILE_BYTES, tid);
  fill512(A1s, tiles + 2 * TILE_BYTES, tid);
  __syncthreads();                       // weights resident

  for (int it = 0; it < 4; ++it) {
    const int r = blockIdx.x * 16 + it * 4 + ri;
    const int l0 = wl * 32 + cb, l1 = l0 + 16;     // row-local l
    const int hu0 = hu[r * 64 + l0], hu1 = hu[r * 64 + l1];
    const int hr0 = hr[r * 64 + l0], hr1 = hr[r * 64 + l1];

    f32x4 acc[16];
    #pragma unroll
    for (int i = 0; i < 16; ++i) acc[i] = (f32x4)(0.f);

    // ---- G1: x = e_uv @ W1 ; A from global image, B from v2e rows
    {
      const float* rp0 = v2e + (size_t)hu0 * DD;
      const float* rp1 = v2e + (size_t)hu1 * DD;
      #pragma unroll
      for (int kk = 0; kk < 4; ++kk) {
        bf16x8 b0 = ldAg(rp0, kk, lane);
        bf16x8 b1 = ldAg(rp1, kk, lane);
        #pragma unroll
        for (int mf = 0; mf < 8; ++mf) {
          bf16x8 a = ldfragG(W1g, mf * 16, kk, lane);
          acc[mf * 2]     = MFMA(a, b0, acc[mf * 2]);
          acc[mf * 2 + 1] = MFMA(a, b1, acc[mf * 2 + 1]);
        }
      }
    }
    // epi1: +R'[hr], relu -> private X (ll rows cb / cb+16)
    #pragma unroll
    for (int mf = 0; mf < 8; ++mf) {
      int f0 = mf * 16 + g * 4;
      float4 r0 = *(const float4*)(Rp + hr0 * DD + f0);
      float4 r1 = *(const float4*)(Rp + hr1 * DD + f0);
      f32x4 v0 = acc[mf * 2], v1 = acc[mf * 2 + 1];
      uint2 p0 = pack4(fmaxf(v0[0] + r0.x, 0.f), fmaxf(v0[1] + r0.y, 0.f),
                       fmaxf(v0[2] + r0.z, 0.f), fmaxf(v0[3] + r0.w, 0.f));
      uint2 p1 = pack4(fmaxf(v1[0] + r1.x, 0.f), fmaxf(v1[1] + r1.y, 0.f),
                       fmaxf(v1[2] + r1.z, 0.f), fmaxf(v1[3] + r1.w, 0.f));
      int o0 = ((cb << 8) + (f0 << 1)) ^ ((cb & 7) << 4);
      int o1 = (((cb + 16) << 8) + (f0 << 1)) ^ ((cb & 7) << 4);
      *(uint2*)(X + o0) = p0;
      *(uint2*)(X + o1) = p1;
    }

    // ---- G2: o = relu(x @ W2 + b2)  (A from LDS, B from private X)
    #pragma unroll
    for (int i = 0; i < 16; ++i) acc[i] = (f32x4)(0.f);
    #pragma unroll
    for (int kk = 0; kk < 4; ++kk) {
      bf16x8 b0 = ldfrag(X, 0, kk, lane);
      bf16x8 b1 = ldfrag(X, 16, kk, lane);
      #pragma unroll
      for (int mf = 0; mf < 8; ++mf) {
        bf16x8 a = ldfrag(W2s, mf * 16, kk, lane);
        acc[mf * 2]     = MFMA(a, b0, acc[mf * 2]);
        acc[mf * 2 + 1] = MFMA(a, b1, acc[mf * 2 + 1]);
      }
    }
    uint2 opk[16];
    #pragma unroll
    for (int mf = 0; mf < 8; ++mf) {
      int f0 = mf * 16 + g * 4;
      float4 bb = *(const float4*)(b2 + f0);
      f32x4 v0 = acc[mf * 2], v1 = acc[mf * 2 + 1];
      uint2 p0 = pack4(fmaxf(v0[0] + bb.x, 0.f), fmaxf(v0[1] + bb.y, 0.f),
                       fmaxf(v0[2] + bb.z, 0.f), fmaxf(v0[3] + bb.w, 0.f));
      uint2 p1 = pack4(fmaxf(v1[0] + bb.x, 0.f), fmaxf(v1[1] + bb.y, 0.f),
                       fmaxf(v1[2] + bb.z, 0.f), fmaxf(v1[3] + bb.w, 0.f));
      opk[mf * 2] = p0; opk[mf * 2 + 1] = p1;
      int o0 = ((cb << 8) + (f0 << 1)) ^ ((cb & 7) << 4);
      int o1 = (((cb + 16) << 8) + (f0 << 1)) ^ ((cb & 7) << 4);
      *(uint2*)(X + o0) = p0;
      *(uint2*)(X + o1) = p1;
    }

    // ---- G3: a1 = relu(o @ a1W + gb)
    #pragma unroll
    for (int i = 0; i < 16; ++i) acc[i] = (f32x4)(0.f);
    #pragma unroll
    for (int kk = 0; kk < 4; ++kk) {
      bf16x8 b0 = ldfrag(X, 0, kk, lane);
      bf16x8 b1 = ldfrag(X, 16, kk, lane);
      #pragma unroll
      for (int mf = 0; mf < 8; ++mf) {
        bf16x8 a = ldfrag(A1s, mf * 16, kk, lane);
        acc[mf * 2]     = MFMA(a, b0, acc[mf * 2]);
        acc[mf * 2 + 1] = MFMA(a, b1, acc[mf * 2 + 1]);
      }
    }
    #pragma unroll
    for (int mf = 0; mf < 8; ++mf) {
      int f0 = mf * 16 + g * 4;
      float4 gv = *(const float4*)(gbv + (size_t)r * DD + f0);
      f32x4 v0 = acc[mf * 2], v1 = acc[mf * 2 + 1];
      uint2 p0 = pack4(fmaxf(v0[0] + gv.x, 0.f), fmaxf(v0[1] + gv.y, 0.f),
                       fmaxf(v0[2] + gv.z, 0.f), fmaxf(v0[3] + gv.w, 0.f));
      uint2 p1 = pack4(fmaxf(v1[0] + gv.x, 0.f), fmaxf(v1[1] + gv.y, 0.f),
                       fmaxf(v1[2] + gv.z, 0.f), fmaxf(v1[3] + gv.w, 0.f));
      int o0 = ((cb << 8) + (f0 << 1)) ^ ((cb & 7) << 4);
      int o1 = (((cb + 16) << 8) + (f0 << 1)) ^ ((cb & 7) << 4);
      *(uint2*)(X + o0) = p0;
      *(uint2*)(X + o1) = p1;
    }

    // ---- G4: a2-pre = a1 @ a2W   (A from global image)
    #pragma unroll
    for (int i = 0; i < 16; ++i) acc[i] = (f32x4)(0.f);
    #pragma unroll
    for (int kk = 0; kk < 4; ++kk) {
      bf16x8 b0 = ldfrag(X, 0, kk, lane);
      bf16x8 b1 = ldfrag(X, 16, kk, lane);
      #pragma unroll
      for (int mf = 0; mf < 8; ++mf) {
        bf16x8 a = ldfragG(A2g, mf * 16, kk, lane);
        acc[mf * 2]     = MFMA(a, b0, acc[mf * 2]);
        acc[mf * 2 + 1] = MFMA(a, b1, acc[mf * 2 + 1]);
      }
    }
    // logits: relu + dot a3W, reduce over g-groups
    {
      float s0 = 0.f, s1 = 0.f;
      #pragma unroll
      for (int mf = 0; mf < 8; ++mf) {
        int f0 = mf * 16 + g * 4;
        float4 ab = *(const float4*)(a2b + f0);
        float4 aw = *(const float4*)(a3W + f0);
        f32x4 v0 = acc[mf * 2], v1 = acc[mf * 2 + 1];
        s0 = fmaf(fmaxf(v0[0] + ab.x, 0.f), aw.x, s0);
        s0 = fmaf(fmaxf(v0[1] + ab.y, 0.f), aw.y, s0);
        s0 = fmaf(fmaxf(v0[2] + ab.z, 0.f), aw.z, s0);
        s0 = fmaf(fmaxf(v0[3] + ab.w, 0.f), aw.w, s0);
        s1 = fmaf(fmaxf(v1[0] + ab.x, 0.f), aw.x, s1);
        s1 = fmaf(fmaxf(v1[1] + ab.y, 0.f), aw.y, s1);
        s1 = fmaf(fmaxf(v1[2] + ab.z, 0.f), aw.z, s1);
        s1 = fmaf(fmaxf(v1[3] + ab.w, 0.f), aw.w, s1);
      }
      s0 += __shfl_xor(s0, 16); s0 += __shfl_xor(s0, 32);
      s1 += __shfl_xor(s1, 16); s1 += __shfl_xor(s1, 32);
      if (g == 0) {
        lpart[ri * 64 + l0] = s0;
        lpart[ri * 64 + l1] = s1;
      }
    }
    __syncthreads();                       // (1) lpart ready

    // masked softmax: computed redundantly by each wave of the row
    float att0, att1;
    {
      float lv = lpart[ri * 64 + lane] + a3bv;
      int len = hlen[r] + 1;
      bool valid = lane < len;
      if (!valid) lv = -1e30f;
      float m = lv;
      #pragma unroll
      for (int off = 32; off; off >>= 1) m = fmaxf(m, __shfl_xor(m, off));
      float pe = valid ? expf(lv - m) : 0.f;
      float su = pe;
      #pragma unroll
      for (int off = 32; off; off >>= 1) su += __shfl_xor(su, off);
      float att = pe / su;
      att0 = __shfl(att, l0);
      att1 = __shfl(att, l1);
    }

    // weighted out-partials from register o; reduce over cb lanes
    {
      float pr[8][4];
      #pragma unroll
      for (int mf = 0; mf < 8; ++mf) {
        uint2 q0 = opk[mf * 2], q1 = opk[mf * 2 + 1];
        pr[mf][0] = att0 * bf2f_lo(q0.x) + att1 * bf2f_lo(q1.x);
        pr[mf][1] = att0 * bf2f_hi(q0.x) + att1 * bf2f_hi(q1.x);
        pr[mf][2] = att0 * bf2f_lo(q0.y) + att1 * bf2f_lo(q1.y);
        pr[mf][3] = att0 * bf2f_hi(q0.y) + att1 * bf2f_hi(q1.y);
      }
      #pragma unroll
      for (int m = 1; m < 16; m <<= 1) {
        #pragma unroll
        for (int mf = 0; mf < 8; ++mf) {
          pr[mf][0] += __shfl_xor(pr[mf][0], m);
          pr[mf][1] += __shfl_xor(pr[mf][1], m);
          pr[mf][2] += __shfl_xor(pr[mf][2], m);
          pr[mf][3] += __shfl_xor(pr[mf][3], m);
        }
      }
      if (cb == 0) {
        float* rd = red + (ri * 2 + wl) * 128;
        #pragma unroll
        for (int mf = 0; mf < 8; ++mf) {
          int f0 = mf * 16 + g * 4;
          *(float4*)(rd + f0) =
              make_float4(pr[mf][0], pr[mf][1], pr[mf][2], pr[mf][3]);
        }
      }
    }
    __syncthreads();                       // (2) red ready

    {
      int rr = tid >> 7, f = tid & 127;
      out[(size_t)(blockIdx.x * 16 + it * 4 + rr) * DD + f] =
          red[rr * 256 + f] + red[rr * 256 + 128 + f];
    }
    // no barrier needed: next lpart/red writes are gated by next-iter barriers
  }
}

extern "C" void kernel_launch(void* const* d_in, const int* in_sizes, int n_in,
                              void* d_out, int out_size, void* d_ws, size_t ws_size,
                              hipStream_t stream) {
  const int*   nodes = (const int*)d_in[0];
  const int*   hu    = (const int*)d_in[1];
  const int*   hr    = (const int*)d_in[2];
  const int*   hlen  = (const int*)d_in[3];
  const float* v2e   = (const float*)d_in[4];
  const float* u2e   = (const float*)d_in[5];
  const float* r2e   = (const float*)d_in[6];
  const float* W1    = (const float*)d_in[7];
  const float* b1    = (const float*)d_in[8];
  const float* W2    = (const float*)d_in[9];
  const float* b2    = (const float*)d_in[10];
  const float* a1W   = (const float*)d_in[11];
  const float* a1b   = (const float*)d_in[12];
  const float* a2W   = (const float*)d_in[13];
  const float* a2b   = (const float*)d_in[14];
  const float* a3W   = (const float*)d_in[15];
  const float* a3b   = (const float*)d_in[16];
  const float* geW   = (const float*)d_in[17];
  const float* geb   = (const float*)d_in[18];
  float* out = (float*)d_out;

  unsigned short* wsw = (unsigned short*)d_ws;
  const char* tiles = (const char*)d_ws;
  float* Rp  = (float*)((char*)d_ws + WS_R_OFF);
  float* gbv = (float*)((char*)d_ws + WS_GB_OFF);

  prep_weights<<<49, 256, 0, stream>>>(W1, W2, a1W, a2W, geW, r2e, b1, wsw, Rp);
  prep_gb<<<256, 256, 0, stream>>>(nodes, u2e, geb, a1b, tiles, gbv);
  main_kernel<<<256, 512, 0, stream>>>(
      hu, hr, hlen, v2e, b2, a2b, a3W, a3b, tiles, Rp, gbv, out);
}

// Round 12
// 113.240 us; speedup vs baseline: 2.8253x; 2.8253x over previous
//
#include <hip/hip_runtime.h>
#include <hip/hip_bf16.h>

#define DD 128
#define TILE_BYTES 32768
#define WS_R_OFF   196608            // 6 tiles * 32768
#define WS_GB_OFF  199168            // + 640*4 (R')

typedef __attribute__((ext_vector_type(8))) short bf16x8;
typedef __attribute__((ext_vector_type(4))) float f32x4;

__device__ inline unsigned short f2bf(float f) {
  unsigned u = __float_as_uint(f);
  return (unsigned short)((u + 0x7fffu + ((u >> 16) & 1u)) >> 16);   // RNE
}
__device__ inline float bf2f_lo(unsigned v) { return __uint_as_float(v << 16); }
__device__ inline float bf2f_hi(unsigned v) { return __uint_as_float(v & 0xffff0000u); }

// packed f32x2 -> bf16x2 (RNE), single VALU op
__device__ inline unsigned cvtpk(float lo, float hi) {
  unsigned r;
  asm("v_cvt_pk_bf16_f32 %0, %1, %2" : "=v"(r) : "v"(lo), "v"(hi));
  return r;
}
__device__ inline uint2 pack4(float v0, float v1, float v2, float v3) {
  return make_uint2(cvtpk(v0, v1), cvtpk(v2, v3));
}

// async global->LDS, 16B per lane (used by prep_gb only)
__device__ inline void async16(void* ldsp, const void* gp) {
  __builtin_amdgcn_global_load_lds(
      (const __attribute__((address_space(1))) void*)gp,
      (__attribute__((address_space(3))) void*)ldsp, 16, 0, 0);
}

// fill a 32 KB LDS slot from a pre-swizzled global image (256 threads)
__device__ inline void fill_w(char* slot, const char* src, int tid) {
  int w = tid >> 6, lane = tid & 63;
  #pragma unroll
  for (int i = 0; i < 8; ++i) {
    int ofs = ((i << 2) + w) << 10;            // 1 KB per wave-chunk
    async16(slot + ofs, src + ofs + lane * 16);
  }
}

// read a 16x32 bf16 MFMA fragment from a swizzled [rows][128] bf16 tile (LDS)
__device__ inline bf16x8 ldfrag(const char* buf, int rowbase, int kk, int lane) {
  int row = rowbase + (lane & 15);
  int off = (row << 8) + (kk << 6) + (lane & 48);
  off ^= (row & 7) << 4;
  return *(const bf16x8*)(buf + off);
}

// same addressing, global pre-swizzled tile image (L2-hot)
__device__ inline bf16x8 ldfragG(const char* gbuf, int rowbase, int kk, int lane) {
  int row = rowbase + (lane & 15);
  int off = (row << 8) + (kk << 6) + (lane & 48);
  off ^= (row & 7) << 4;
  return *(const bf16x8*)(gbuf + off);
}

// build a fragment directly from a global fp32 row (8 floats -> bf16x8)
__device__ inline bf16x8 ldAg(const float* rp, int kk, int lane) {
  const float4* p = (const float4*)(rp + (kk << 5) + ((lane >> 4) << 3));
  float4 f0 = p[0], f1 = p[1];
  uint4 u = make_uint4(cvtpk(f0.x, f0.y), cvtpk(f0.z, f0.w),
                       cvtpk(f1.x, f1.y), cvtpk(f1.z, f1.w));
  return __builtin_bit_cast(bf16x8, u);
}

#define MFMA(a, b, c) __builtin_amdgcn_mfma_f32_16x16x32_bf16((a), (b), (c), 0, 0, 0)

// ---------------- pre-kernel 1: weight tiles (bf16, [n][k], pre-swizzled) + R' ----------------
__global__ __launch_bounds__(256) void prep_weights(
    const float* __restrict__ W1, const float* __restrict__ W2,
    const float* __restrict__ a1W, const float* __restrict__ a2W,
    const float* __restrict__ geW,
    const float* __restrict__ r2e, const float* __restrict__ b1,
    unsigned short* __restrict__ wsw, float* __restrict__ Rp) {
  int gid = blockIdx.x * 256 + threadIdx.x;
  if (gid < 12288) {
    int tile = gid >> 11, idx = gid & 2047;
    int row = idx >> 4, slot = idx & 15;
    int slot2 = slot ^ (row & 7);              // inverse swizzle on source
    const float* W; int kb;
    switch (tile) {
      case 0:  W = W1;  kb = 0;   break;       // W1[:128]
      case 1:  W = W2;  kb = 0;   break;
      case 2:  W = a1W; kb = 0;   break;       // a1W[:128]
      case 3:  W = a2W; kb = 0;   break;
      case 4:  W = geW; kb = 0;   break;
      default: W = a1W; kb = 128; break;       // a1W[128:]
    }
    unsigned pk[4];
    #pragma unroll
    for (int p = 0; p < 4; ++p) {
      unsigned short lo = f2bf(W[(size_t)(kb + slot2 * 8 + 2 * p) * DD + row]);
      unsigned short hi = f2bf(W[(size_t)(kb + slot2 * 8 + 2 * p + 1) * DD + row]);
      pk[p] = (unsigned)lo | ((unsigned)hi << 16);
    }
    *(uint4*)(wsw + (size_t)tile * 16384 + (size_t)idx * 8) =
        make_uint4(pk[0], pk[1], pk[2], pk[3]);
  } else {
    // R'[5][128] = r2e @ W1[128:] + b1   (fp32 exact)
    int t = gid - 12288;
    for (int idx = t; idx < 640; idx += 256) {
      int r = idx >> 7, d = idx & 127;
      float s = b1[d];
      for (int k = 0; k < 128; ++k)
        s = fmaf(r2e[r * DD + k], W1[(size_t)(DD + k) * DD + d], s);
      Rp[idx] = s;
    }
  }
}

// ---------------- pre-kernel 2: gb[b][d] = a1b + relu(mean@geW+geb)@a1W[D:] ----------------
__global__ __launch_bounds__(256, 2) void prep_gb(
    const int* __restrict__ nodes, const float* __restrict__ u2e,
    const float* __restrict__ geb, const float* __restrict__ a1b,
    const char* __restrict__ tiles, float* __restrict__ gbv) {
  __shared__ char mean_s[4096];    // [16][128] bf16 swizzled
  __shared__ char g_s[4096];
  __shared__ char wslot[32768];
  __shared__ int nodes_s[128];
  int tid = threadIdx.x, w = tid >> 6, lane = tid & 63;
  int b0 = blockIdx.x * 16;
  if (tid < 128) nodes_s[tid] = nodes[b0 * 8 + tid];
  fill_w(wslot, tiles + 4 * TILE_BYTES, tid);      // geW
  __syncthreads();
  for (int idx = tid; idx < 2048; idx += 256) {
    int row = idx >> 7, d = idx & 127;
    float m = 0.f;
    #pragma unroll
    for (int j = 0; j < 8; ++j)
      m += u2e[(size_t)nodes_s[row * 8 + j] * DD + d];
    m *= 0.125f;
    int off = ((row << 8) + (d << 1)) ^ ((row & 7) << 4);
    *(unsigned short*)(mean_s + off) = f2bf(m);
  }
  __syncthreads();
  int cb = lane & 15, rb = (lane >> 4) << 2;
  f32x4 acc[2] = {(f32x4)(0.f), (f32x4)(0.f)};
  #pragma unroll
  for (int kk = 0; kk < 4; ++kk) {
    bf16x8 a = ldfrag(mean_s, 0, kk, lane);
    #pragma unroll
    for (int nf = 0; nf < 2; ++nf) {
      bf16x8 b = ldfrag(wslot, w * 32 + nf * 16, kk, lane);
      acc[nf] = MFMA(a, b, acc[nf]);
    }
  }
  __syncthreads();
  fill_w(wslot, tiles + 5 * TILE_BYTES, tid);      // a1W[128:]
  #pragma unroll
  for (int nf = 0; nf < 2; ++nf) {
    int col = w * 32 + nf * 16 + cb;
    float gb2 = geb[col];
    #pragma unroll
    for (int j = 0; j < 4; ++j) {
      int row = rb + j;
      float v = fmaxf(acc[nf][j] + gb2, 0.f);
      int off = ((row << 8) + (col << 1)) ^ ((row & 7) << 4);
      *(unsigned short*)(g_s + off) = f2bf(v);
    }
  }
  __syncthreads();
  acc[0] = (f32x4)(0.f); acc[1] = (f32x4)(0.f);
  #pragma unroll
  for (int kk = 0; kk < 4; ++kk) {
    bf16x8 a = ldfrag(g_s, 0, kk, lane);
    #pragma unroll
    for (int nf = 0; nf < 2; ++nf) {
      bf16x8 b = ldfrag(wslot, w * 32 + nf * 16, kk, lane);
      acc[nf] = MFMA(a, b, acc[nf]);
    }
  }
  #pragma unroll
  for (int nf = 0; nf < 2; ++nf) {
    int col = w * 32 + nf * 16 + cb;
    float bb = a1b[col];
    #pragma unroll
    for (int j = 0; j < 4; ++j)
      gbv[(size_t)(b0 + rb + j) * DD + col] = acc[nf][j] + bb;
  }
}

// 64f x 32l wave-tile GEMM over K=128: A from GLOBAL pre-swizzled image, B from LDS X
__device__ inline void gemmG(f32x4 acc[8], const char* Wg, const char* Xt,
                             int mfw, int nlw, int lane) {
  #pragma unroll
  for (int kk = 0; kk < 4; ++kk) {
    bf16x8 bf0 = ldfrag(Xt, nlw * 32, kk, lane);
    bf16x8 bf1 = ldfrag(Xt, nlw * 32 + 16, kk, lane);
    #pragma unroll
    for (int mf = 0; mf < 4; ++mf) {
      bf16x8 a = ldfragG(Wg, mfw * 64 + mf * 16, kk, lane);
      acc[mf * 2]     = MFMA(a, bf0, acc[mf * 2]);
      acc[mf * 2 + 1] = MFMA(a, bf1, acc[mf * 2 + 1]);
    }
  }
}

// ---------------- main: 1 row/block, 4 waves, NO weight LDS (A from L2), 8 barriers ----------------
__global__ __launch_bounds__(256, 4) void main_kernel(
    const int* __restrict__ hu, const int* __restrict__ hr,
    const int* __restrict__ hlen,
    const float* __restrict__ v2e,
    const float* __restrict__ b2, const float* __restrict__ a2b,
    const float* __restrict__ a3W, const float* __restrict__ a3b,
    const char* __restrict__ tiles, const float* __restrict__ Rp,
    const float* __restrict__ gbv, float* __restrict__ out) {
  __shared__ char X[16384];          // x -> o -> a1 (in-place, barrier-separated)
  __shared__ float lpart[2][64];
  __shared__ float att_s[64];
  __shared__ float red_s[2][128];

  const int tid = threadIdx.x, lane = tid & 63;
  const int wv = tid >> 6;
  const int mfw = wv >> 1, nlw = wv & 1;   // 64f x 32l wave tile
  const int cb = lane & 15, g = lane >> 4;
  const int b0 = blockIdx.x;
  const char* W1g = tiles;
  const char* W2g = tiles + TILE_BYTES;
  const char* A1g = tiles + 2 * TILE_BYTES;
  const char* A2g = tiles + 3 * TILE_BYTES;

  const int l0 = nlw * 32 + cb, l1 = l0 + 16;
  const int hu0 = hu[b0 * 64 + l0], hu1 = hu[b0 * 64 + l1];
  const int hr0 = hr[b0 * 64 + l0], hr1 = hr[b0 * 64 + l1];

  f32x4 acc[8];
  #pragma unroll
  for (int i = 0; i < 8; ++i) acc[i] = (f32x4)(0.f);

  // ---- G1: x = e_uv @ W1 ; A from global image, B from v2e rows
  {
    const float* rp0 = v2e + (size_t)hu0 * DD;
    const float* rp1 = v2e + (size_t)hu1 * DD;
    #pragma unroll
    for (int kk = 0; kk < 4; ++kk) {
      bf16x8 bf0 = ldAg(rp0, kk, lane);
      bf16x8 bf1 = ldAg(rp1, kk, lane);
      #pragma unroll
      for (int mf = 0; mf < 4; ++mf) {
        bf16x8 a = ldfragG(W1g, mfw * 64 + mf * 16, kk, lane);
        acc[mf * 2]     = MFMA(a, bf0, acc[mf * 2]);
        acc[mf * 2 + 1] = MFMA(a, bf1, acc[mf * 2 + 1]);
      }
    }
  }
  // epi1: +R'[hr] (global, L2-hot), relu -> X
  #pragma unroll
  for (int mf = 0; mf < 4; ++mf) {
    int f0 = mfw * 64 + mf * 16 + g * 4;
    float4 r0 = *(const float4*)(Rp + hr0 * DD + f0);
    float4 r1 = *(const float4*)(Rp + hr1 * DD + f0);
    f32x4 v0 = acc[mf * 2], v1 = acc[mf * 2 + 1];
    uint2 p0 = pack4(fmaxf(v0[0] + r0.x, 0.f), fmaxf(v0[1] + r0.y, 0.f),
                     fmaxf(v0[2] + r0.z, 0.f), fmaxf(v0[3] + r0.w, 0.f));
    uint2 p1 = pack4(fmaxf(v1[0] + r1.x, 0.f), fmaxf(v1[1] + r1.y, 0.f),
                     fmaxf(v1[2] + r1.z, 0.f), fmaxf(v1[3] + r1.w, 0.f));
    int o0 = ((l0 << 8) + (f0 << 1)) ^ ((l0 & 7) << 4);
    int o1 = ((l1 << 8) + (f0 << 1)) ^ ((l1 & 7) << 4);
    *(uint2*)(X + o0) = p0;
    *(uint2*)(X + o1) = p1;
  }
  __syncthreads();                       // (1) x ready

  // ---- G2: o = relu(x @ W2 + b2); keep packed o in regs
  #pragma unroll
  for (int i = 0; i < 8; ++i) acc[i] = (f32x4)(0.f);
  gemmG(acc, W2g, X, mfw, nlw, lane);
  __syncthreads();                       // (2) done reading x
  uint2 opk[8];
  #pragma unroll
  for (int mf = 0; mf < 4; ++mf) {
    int f0 = mfw * 64 + mf * 16 + g * 4;
    float4 bb = *(const float4*)(b2 + f0);
    f32x4 v0 = acc[mf * 2], v1 = acc[mf * 2 + 1];
    uint2 p0 = pack4(fmaxf(v0[0] + bb.x, 0.f), fmaxf(v0[1] + bb.y, 0.f),
                     fmaxf(v0[2] + bb.z, 0.f), fmaxf(v0[3] + bb.w, 0.f));
    uint2 p1 = pack4(fmaxf(v1[0] + bb.x, 0.f), fmaxf(v1[1] + bb.y, 0.f),
                     fmaxf(v1[2] + bb.z, 0.f), fmaxf(v1[3] + bb.w, 0.f));
    opk[mf * 2] = p0; opk[mf * 2 + 1] = p1;
    int o0 = ((l0 << 8) + (f0 << 1)) ^ ((l0 & 7) << 4);
    int o1 = ((l1 << 8) + (f0 << 1)) ^ ((l1 & 7) << 4);
    *(uint2*)(X + o0) = p0;
    *(uint2*)(X + o1) = p1;
  }
  __syncthreads();                       // (3) o ready

  // ---- G3: a1 = relu(o @ a1W[:128] + gb)
  #pragma unroll
  for (int i = 0; i < 8; ++i) acc[i] = (f32x4)(0.f);
  gemmG(acc, A1g, X, mfw, nlw, lane);
  __syncthreads();                       // (4) done reading o
  #pragma unroll
  for (int mf = 0; mf < 4; ++mf) {
    int f0 = mfw * 64 + mf * 16 + g * 4;
    float4 gv = *(const float4*)(gbv + (size_t)b0 * DD + f0);
    f32x4 v0 = acc[mf * 2], v1 = acc[mf * 2 + 1];
    uint2 p0 = pack4(fmaxf(v0[0] + gv.x, 0.f), fmaxf(v0[1] + gv.y, 0.f),
                     fmaxf(v0[2] + gv.z, 0.f), fmaxf(v0[3] + gv.w, 0.f));
    uint2 p1 = pack4(fmaxf(v1[0] + gv.x, 0.f), fmaxf(v1[1] + gv.y, 0.f),
                     fmaxf(v1[2] + gv.z, 0.f), fmaxf(v1[3] + gv.w, 0.f));
    int o0 = ((l0 << 8) + (f0 << 1)) ^ ((l0 & 7) << 4);
    int o1 = ((l1 << 8) + (f0 << 1)) ^ ((l1 & 7) << 4);
    *(uint2*)(X + o0) = p0;
    *(uint2*)(X + o1) = p1;
  }
  __syncthreads();                       // (5) a1 ready

  // ---- G4: logits = relu(a1 @ a2W + a2b) @ a3W  (A from global image)
  #pragma unroll
  for (int i = 0; i < 8; ++i) acc[i] = (f32x4)(0.f);
  gemmG(acc, A2g, X, mfw, nlw, lane);
  {
    float s0 = 0.f, s1 = 0.f;
    #pragma unroll
    for (int mf = 0; mf < 4; ++mf) {
      int f0 = mfw * 64 + mf * 16 + g * 4;
      float4 ab = *(const float4*)(a2b + f0);
      float4 aw = *(const float4*)(a3W + f0);
      f32x4 v0 = acc[mf * 2], v1 = acc[mf * 2 + 1];
      s0 = fmaf(fmaxf(v0[0] + ab.x, 0.f), aw.x, s0);
      s0 = fmaf(fmaxf(v0[1] + ab.y, 0.f), aw.y, s0);
      s0 = fmaf(fmaxf(v0[2] + ab.z, 0.f), aw.z, s0);
      s0 = fmaf(fmaxf(v0[3] + ab.w, 0.f), aw.w, s0);
      s1 = fmaf(fmaxf(v1[0] + ab.x, 0.f), aw.x, s1);
      s1 = fmaf(fmaxf(v1[1] + ab.y, 0.f), aw.y, s1);
      s1 = fmaf(fmaxf(v1[2] + ab.z, 0.f), aw.z, s1);
      s1 = fmaf(fmaxf(v1[3] + ab.w, 0.f), aw.w, s1);
    }
    s0 += __shfl_xor(s0, 16); s0 += __shfl_xor(s0, 32);
    s1 += __shfl_xor(s1, 16); s1 += __shfl_xor(s1, 32);
    if (g == 0) { lpart[mfw][l0] = s0; lpart[mfw][l1] = s1; }
  }
  __syncthreads();                       // (6) lpart ready

  // ---- masked softmax over L=64 (wave 0)
  if (tid < 64) {
    float lv = lpart[0][tid] + lpart[1][tid] + a3b[0];
    int len = hlen[b0] + 1;
    bool valid = tid < len;
    if (!valid) lv = -1e30f;
    float m = lv;
    #pragma unroll
    for (int off = 32; off; off >>= 1) m = fmaxf(m, __shfl_xor(m, off));
    float pe = valid ? expf(lv - m) : 0.f;
    float s = pe;
    #pragma unroll
    for (int off = 32; off; off >>= 1) s += __shfl_xor(s, off);
    att_s[tid] = pe / s;
  }
  __syncthreads();                       // (7) att ready

  // ---- out partials from register o copy; reduce over cb lanes
  {
    float att0 = att_s[l0], att1 = att_s[l1];
    float pr[4][4];
    #pragma unroll
    for (int mf = 0; mf < 4; ++mf) {
      uint2 q0 = opk[mf * 2], q1 = opk[mf * 2 + 1];
      pr[mf][0] = att0 * bf2f_lo(q0.x) + att1 * bf2f_lo(q1.x);
      pr[mf][1] = att0 * bf2f_hi(q0.x) + att1 * bf2f_hi(q1.x);
      pr[mf][2] = att0 * bf2f_lo(q0.y) + att1 * bf2f_lo(q1.y);
      pr[mf][3] = att0 * bf2f_hi(q0.y) + att1 * bf2f_hi(q1.y);
    }
    #pragma unroll
    for (int m = 1; m < 16; m <<= 1) {
      #pragma unroll
      for (int mf = 0; mf < 4; ++mf) {
        pr[mf][0] += __shfl_xor(pr[mf][0], m);
        pr[mf][1] += __shfl_xor(pr[mf][1], m);
        pr[mf][2] += __shfl_xor(pr[mf][2], m);
        pr[mf][3] += __shfl_xor(pr[mf][3], m);
      }
    }
    if (cb == 0) {
      #pragma unroll
      for (int mf = 0; mf < 4; ++mf) {
        int f0 = mfw * 64 + mf * 16 + g * 4;
        red_s[nlw][f0 + 0] = pr[mf][0];
        red_s[nlw][f0 + 1] = pr[mf][1];
        red_s[nlw][f0 + 2] = pr[mf][2];
        red_s[nlw][f0 + 3] = pr[mf][3];
      }
    }
  }
  __syncthreads();                       // (8) red ready

  if (tid < 128)
    out[(size_t)b0 * DD + tid] = red_s[0][tid] + red_s[1][tid];
}

extern "C" void kernel_launch(void* const* d_in, const int* in_sizes, int n_in,
                              void* d_out, int out_size, void* d_ws, size_t ws_size,
                              hipStream_t stream) {
  const int*   nodes = (const int*)d_in[0];
  const int*   hu    = (const int*)d_in[1];
  const int*   hr    = (const int*)d_in[2];
  const int*   hlen  = (const int*)d_in[3];
  const float* v2e   = (const float*)d_in[4];
  const float* u2e   = (const float*)d_in[5];
  const float* r2e   = (const float*)d_in[6];
  const float* W1    = (const float*)d_in[7];
  const float* b1    = (const float*)d_in[8];
  const float* W2    = (const float*)d_in[9];
  const float* b2    = (const float*)d_in[10];
  const float* a1W   = (const float*)d_in[11];
  const float* a1b   = (const float*)d_in[12];
  const float* a2W   = (const float*)d_in[13];
  const float* a2b   = (const float*)d_in[14];
  const float* a3W   = (const float*)d_in[15];
  const float* a3b   = (const float*)d_in[16];
  const float* geW   = (const float*)d_in[17];
  const float* geb   = (const float*)d_in[18];
  float* out = (float*)d_out;

  unsigned short* wsw = (unsigned short*)d_ws;
  const char* tiles = (const char*)d_ws;
  float* Rp  = (float*)((char*)d_ws + WS_R_OFF);
  float* gbv = (float*)((char*)d_ws + WS_GB_OFF);

  prep_weights<<<49, 256, 0, stream>>>(W1, W2, a1W, a2W, geW, r2e, b1, wsw, Rp);
  prep_gb<<<256, 256, 0, stream>>>(nodes, u2e, geb, a1b, tiles, gbv);
  main_kernel<<<4096, 256, 0, stream>>>(
      hu, hr, hlen, v2e, b2, a2b, a3W, a3b, tiles, Rp, gbv, out);
}